// Round 6
// baseline (1822.781 us; speedup 1.0000x reference)
//
#include <hip/hip_runtime.h>
#include <math.h>

namespace {
constexpr int kS = 2048;
constexpr int kD = 64;
constexpr int kBH = 32;              // B*H = 2*16
constexpr int kTopK = 32;
constexpr int kPadBins = 2112;       // 2048 bins (11-bit) + 64 pad words
constexpr int kCandCap = 128;        // pivot-bin candidates
constexpr int kKeepCap = 64;         // kept (idx, weight) list cap
constexpr size_t kCtxElems  = (size_t)kBH * kS * kD;   // 4,194,304
constexpr size_t kAttnElems = (size_t)kBH * kS * kS;   // 134,217,728
}

typedef float f2 __attribute__((ext_vector_type(2)));

__device__ __forceinline__ unsigned sortable_bits(float x) {
  unsigned u = __float_as_uint(x);
  return u ^ ((u & 0x80000000u) ? 0xFFFFFFFFu : 0x80000000u);
}

// ---------------------------------------------------------------------------
// Kernel 1: scores = Q K^T / 8, fp32. Round-2 empirical best, UNCHANGED
// (128x128 tile, 8x8 microtile, pk_fma, two-half K-staging).
// BIT-EXACTNESS INVARIANT: every score element is a single fp32 fused-FMA
// chain `acc += a*b` with d STRICTLY ASCENDING (half outer, kk inner),
// scaled by 0.125f at the end; f2 pairing along j = independent chains.
//
// DIAGNOSTIC THIS ROUND: launched 3x (idempotent -- same q,k -> same bytes
// in the scores region; k2 runs once afterwards). dur_us = base + 2*t_k1
// finally yields the k1/k2 time split that five rounds of theory lacked.
// ---------------------------------------------------------------------------
__global__ __launch_bounds__(256) void qk_scores(const float* __restrict__ q,
                                                 const float* __restrict__ k,
                                                 float* __restrict__ scores) {
  __shared__ float QsT[32][132];  // [kk][q-row]  16.9 KB
  __shared__ float KsT[32][132];  // [kk][k-row]  16.9 KB
  const int bh  = blockIdx.z;
  const int q0  = blockIdx.y * 128;
  const int k0  = blockIdx.x * 128;
  const int tid = threadIdx.x;
  const float* qg = q + ((size_t)bh * kS + q0) * kD;   // 128 rows x 64
  const float* kg = k + ((size_t)bh * kS + k0) * kD;

  const int ty8 = (tid >> 4) * 8;   // q rows ty8..ty8+7
  const int tx8 = (tid & 15) * 8;   // k cols tx8..tx8+7
  f2 acc[8][4] = {};                // acc[i][j2] = cols {2*j2, 2*j2+1}

  for (int half = 0; half < 2; ++half) {
    if (half) __syncthreads();       // waves done reading previous half
#pragma unroll
    for (int rnd = 0; rnd < 4; ++rnd) {
      int flat = rnd * 1024 + tid * 4;   // 128 rows x 32 cols per half
      int r = flat >> 5;                 // tile row 0..127
      int c = flat & 31;                 // kk within half (mult of 4)
      float4 qv = *(const float4*)(qg + r * kD + half * 32 + c);
      QsT[c + 0][r] = qv.x;
      QsT[c + 1][r] = qv.y;
      QsT[c + 2][r] = qv.z;
      QsT[c + 3][r] = qv.w;
      float4 kv = *(const float4*)(kg + r * kD + half * 32 + c);
      KsT[c + 0][r] = kv.x;
      KsT[c + 1][r] = kv.y;
      KsT[c + 2][r] = kv.z;
      KsT[c + 3][r] = kv.w;
    }
    __syncthreads();

#pragma unroll
    for (int kk = 0; kk < 32; ++kk) {
      float a[8];
      f2 b[4];
      *(float4*)(&a[0]) = *(const float4*)(&QsT[kk][ty8]);
      *(float4*)(&a[4]) = *(const float4*)(&QsT[kk][ty8 + 4]);
      float4 b0 = *(const float4*)(&KsT[kk][tx8]);
      float4 b1 = *(const float4*)(&KsT[kk][tx8 + 4]);
      b[0] = f2{b0.x, b0.y};
      b[1] = f2{b0.z, b0.w};
      b[2] = f2{b1.x, b1.y};
      b[3] = f2{b1.z, b1.w};
      // Per-element d order: half outer, kk inner ascending -> frozen chain.
#pragma unroll
      for (int i = 0; i < 8; ++i) {
        const f2 as = {a[i], a[i]};
#pragma unroll
        for (int j2 = 0; j2 < 4; ++j2)
          acc[i][j2] += as * b[j2];    // -> v_pk_fma_f32 (2 fused chains)
      }
    }
  }

#pragma unroll
  for (int i = 0; i < 8; ++i) {
    float* orow = scores + ((size_t)bh * kS + q0 + ty8 + i) * kS + k0 + tx8;
    float4 o0 = make_float4(acc[i][0].x * 0.125f, acc[i][0].y * 0.125f,
                            acc[i][1].x * 0.125f, acc[i][1].y * 0.125f);
    float4 o1 = make_float4(acc[i][2].x * 0.125f, acc[i][2].y * 0.125f,
                            acc[i][3].x * 0.125f, acc[i][3].y * 0.125f);
    *(float4*)(orow)     = o0;
    *(float4*)(orow + 4) = o1;
  }
}

// ---------------------------------------------------------------------------
// Kernel 2: UNCHANGED since round 2 (byte-identical). Selection semantics:
//   t32 = 32nd-largest fp32 VALUE (duplicates counted), keep = score >= t32.
// ---------------------------------------------------------------------------
__global__ __launch_bounds__(256) void topk_softmax(const float* __restrict__ v,
                                                    float* __restrict__ ctx,
                                                    float* __restrict__ attn,
                                                    float* __restrict__ mask) {
  __shared__ unsigned s_hist[4][kPadBins];   // 33 KB (8.25 KB / wave)
  __shared__ float    s_cand[4][kCandCap];   // 2 KB
  __shared__ int      s_kidx[4][kKeepCap];   // 1 KB
  __shared__ float    s_kw[4][kKeepCap];     // 1 KB
  __shared__ unsigned s_nc[4];

  const int tid  = threadIdx.x;
  const int wid  = tid >> 6;
  const int lane = tid & 63;
  const int row  = blockIdx.x * 4 + wid;     // bh*2048 + qi
  const int bh   = row >> 11;
  unsigned* hist = s_hist[wid];

  // P0: load this row's 2048 scores, 32/lane (8 x float4, coalesced).
  const float* srow = attn + (size_t)row * kS;   // scores from kernel 1
  float locv[32];
#pragma unroll
  for (int g = 0; g < 8; ++g)
    *(float4*)(&locv[g * 4]) = *(const float4*)(srow + g * 256 + lane * 4);

  // zero padded hist (2112 = 33*64, stride-64 -> 2-way = free) + counter
#pragma unroll
  for (int j = 0; j < 33; ++j) hist[j * 64 + lane] = 0u;
  if (lane == 0) s_nc[wid] = 0u;

  // P1: histogram (11-bit sortable prefix) + row max.
  float pmax = locv[0];
#pragma unroll
  for (int j = 0; j < 32; ++j) {
    unsigned b = sortable_bits(locv[j]) >> 21;
    atomicAdd(&hist[b + (b >> 5)], 1u);
    pmax = fmaxf(pmax, locv[j]);
  }
#pragma unroll
  for (int off = 32; off >= 1; off >>= 1)
    pmax = fmaxf(pmax, __shfl_xor(pmax, off));

  asm volatile("s_waitcnt lgkmcnt(0)" ::: "memory");

  // P2: per-lane chunk sums (bins [32*lane, 32*lane+32)) + in-wave suffix scan.
  unsigned lsum = 0;
#pragma unroll
  for (int j = 0; j < 32; ++j) lsum += hist[lane * 33 + j];   // padded idx
  unsigned sfx = lsum;
#pragma unroll
  for (int off = 1; off < 64; off <<= 1) {
    unsigned z = __shfl_down(sfx, off);
    if (lane + off < 64) sfx += z;
  }
  const unsigned above = sfx - lsum;   // elements in chunks strictly above mine

  // P3: locate pivot bin (exactly one lane crosses kTopK).
  int bstar = 0, gabove = 0;
  const bool ispiv = (sfx >= (unsigned)kTopK) && (above < (unsigned)kTopK);
  if (ispiv) {
    unsigned run = above;
    for (int j = 31; j >= 0; --j) {
      unsigned h = hist[lane * 33 + j];
      if (run < (unsigned)kTopK && run + h >= (unsigned)kTopK) {
        bstar  = lane * 32 + j;
        gabove = (int)run;
      }
      run += h;
    }
  }
  const unsigned long long pm = __ballot(ispiv);
  const int psrc = __ffsll(pm) - 1;
  bstar  = __shfl(bstar, psrc);
  gabove = __shfl(gabove, psrc);

  // P4: collect pivot-bin candidates (equal values all share the pivot bin).
#pragma unroll
  for (int j = 0; j < 32; ++j) {
    unsigned b = sortable_bits(locv[j]) >> 21;
    if ((int)b == bstar) {
      unsigned p = atomicAdd(&s_nc[wid], 1u);
      if (p < (unsigned)kCandCap) s_cand[wid][p] = locv[j];
    }
  }
  asm volatile("s_waitcnt lgkmcnt(0)" ::: "memory");
  const int m = (int)min(s_nc[wid], (unsigned)kCandCap);

  // P5: t32 = value with gabove+g < 32 <= gabove+g+e. Lane i refines
  // candidates i and i+64; winner found via ballot, broadcast via shfl.
  const float x0 = (lane < m) ? s_cand[wid][lane] : 0.0f;
  const float x1 = (lane + 64 < m) ? s_cand[wid][lane + 64] : 0.0f;
  int g0 = 0, e0 = 0, g1 = 0, e1 = 0;
  for (int j = 0; j < m; ++j) {
    float y = s_cand[wid][j];   // broadcast read
    g0 += (y > x0); e0 += (y == x0);
    g1 += (y > x1); e1 += (y == x1);
  }
  const bool win0 = (lane < m) &&
                    (gabove + g0 < kTopK) && (gabove + g0 + e0 >= kTopK);
  const bool win1 = (lane + 64 < m) &&
                    (gabove + g1 < kTopK) && (gabove + g1 + e1 >= kTopK);
  const unsigned long long wm0 = __ballot(win0);
  const unsigned long long wm1 = __ballot(win1);
  float t32;
  if (wm0 != 0ull)      t32 = __shfl(x0, __ffsll(wm0) - 1);
  else if (wm1 != 0ull) t32 = __shfl(x1, __ffsll(wm1) - 1);
  else                  t32 = pmax;   // unreachable (cap never hit)

  // P6: weights, Z, kept-list via ballot/popc compaction (no LDS atomics;
  // deterministic j-major, lane-minor list order). Same numerics:
  // w = __expf(score - rowmax) for kept, 0 otherwise.
  const unsigned long long below = (1ull << lane) - 1ull;
  float w32[32];
  float psum = 0.0f;
  int nkbase = 0;
#pragma unroll
  for (int j = 0; j < 32; ++j) {
    const bool keep = (locv[j] >= t32);
    const float wv = keep ? __expf(locv[j] - pmax) : 0.0f;
    w32[j] = wv;
    psum += wv;
    const unsigned long long mk = __ballot(keep);
    if (keep) {
      const int slot = nkbase + (int)__popcll(mk & below);
      if (slot < kKeepCap) {
        s_kidx[wid][slot] = (j >> 2) * 256 + lane * 4 + (j & 3);  // key index
        s_kw[wid][slot]   = wv;
      }
    }
    nkbase += (int)__popcll(mk);
  }
  const int nk = nkbase < kKeepCap ? nkbase : kKeepCap;
#pragma unroll
  for (int off = 32; off >= 1; off >>= 1)
    psum += __shfl_xor(psum, off);
  const float invZ = 1.0f / psum;

  // P7: write attn + mask straight from registers (coalesced float4).
  float* arow = attn + (size_t)row * kS;
  float* mrow = mask + (size_t)row * kS;
#pragma unroll
  for (int g = 0; g < 8; ++g) {
    float4 a = make_float4(w32[g*4+0] * invZ, w32[g*4+1] * invZ,
                           w32[g*4+2] * invZ, w32[g*4+3] * invZ);
    float4 mm = make_float4(locv[g*4+0] >= t32 ? 0.f : 1.f,
                            locv[g*4+1] >= t32 ? 0.f : 1.f,
                            locv[g*4+2] >= t32 ? 0.f : 1.f,
                            locv[g*4+3] >= t32 ? 0.f : 1.f);
    *(float4*)(arow + g * 256 + lane * 4) = a;
    *(float4*)(mrow + g * 256 + lane * 4) = mm;
  }

  // P8: context. ALL 64 lanes (lane = dim d), 8-deep batched v loads (L2-hot,
  // coalesced 256B per row), single accumulator in deterministic slot order.
  asm volatile("s_waitcnt lgkmcnt(0)" ::: "memory");
  const float* vb = v + ((size_t)bh * kS) * kD + lane;
  float acc = 0.0f;
  int c = 0;
  for (; c + 8 <= nk; c += 8) {
    float w[8], vv[8];
    int   ii[8];
#pragma unroll
    for (int u = 0; u < 8; ++u) {
      w[u]  = s_kw[wid][c + u];
      ii[u] = s_kidx[wid][c + u];
    }
#pragma unroll
    for (int u = 0; u < 8; ++u)
      vv[u] = vb[(size_t)ii[u] * kD];
#pragma unroll
    for (int u = 0; u < 8; ++u)
      acc += w[u] * vv[u];
  }
  for (; c < nk; ++c)
    acc += s_kw[wid][c] * vb[(size_t)s_kidx[wid][c] * kD];
  ctx[(size_t)row * kD + lane] = acc * invZ;
}

// ---------------------------------------------------------------------------
// Launch: round-2 monolithic schedule, but qk_scores runs 3x (idempotent) as
// a timing probe: dur_us = base + 2*t_k1 isolates the k1/k2 split that the
// fill-dominated top-5 counters cannot show.
// ---------------------------------------------------------------------------
extern "C" void kernel_launch(void* const* d_in, const int* in_sizes, int n_in,
                              void* d_out, int out_size, void* d_ws, size_t ws_size,
                              hipStream_t stream) {
  const float* q = (const float*)d_in[0];
  const float* k = (const float*)d_in[1];
  const float* v = (const float*)d_in[2];
  float* out  = (float*)d_out;
  float* ctx  = out;
  float* attn = out + kCtxElems;
  float* mask = attn + kAttnElems;

  dim3 g1(kS / 128, kS / 128, kBH);
  qk_scores<<<g1, 256, 0, stream>>>(q, k, attn);
  qk_scores<<<g1, 256, 0, stream>>>(q, k, attn);   // timing probe (idempotent)
  qk_scores<<<g1, 256, 0, stream>>>(q, k, attn);   // timing probe (idempotent)
  topk_softmax<<<dim3(kBH * kS / 4), 256, 0, stream>>>(v, ctx, attn, mask);
}

// Round 7
// 1535.914 us; speedup vs baseline: 1.1868x; 1.1868x over previous
//
#include <hip/hip_runtime.h>
#include <math.h>

namespace {
constexpr int kS = 2048;
constexpr int kD = 64;
constexpr int kBH = 32;              // B*H = 2*16
constexpr int kTopK = 32;
constexpr int kPadWords = 1088;      // 1024 packed hist words + 64 pad (17/lane)
constexpr int kCandCap = 128;        // pivot-bin candidates
constexpr int kKeepCap = 64;         // kept (idx, weight) list cap
constexpr size_t kCtxElems  = (size_t)kBH * kS * kD;   // 4,194,304
constexpr size_t kAttnElems = (size_t)kBH * kS * kS;   // 134,217,728
}

typedef float f2 __attribute__((ext_vector_type(2)));

__device__ __forceinline__ unsigned sortable_bits(float x) {
  unsigned u = __float_as_uint(x);
  return u ^ ((u & 0x80000000u) ? 0xFFFFFFFFu : 0x80000000u);
}

// ---------------------------------------------------------------------------
// Kernel 1: scores = Q K^T / 8, fp32. Round-2 empirical best, FROZEN
// (128x128 tile, 8x8 microtile, pk_fma, two-half staging). R6 probe: 224 us,
// ~60 us above its max(compute,write) floor -- not the target.
// BIT-EXACTNESS INVARIANT: single fp32 fused-FMA chain per element, d
// ascending, *0.125f at the end; f2 pairing along j = independent chains.
// ---------------------------------------------------------------------------
__global__ __launch_bounds__(256) void qk_scores(const float* __restrict__ q,
                                                 const float* __restrict__ k,
                                                 float* __restrict__ scores) {
  __shared__ float QsT[32][132];  // [kk][q-row]  16.9 KB
  __shared__ float KsT[32][132];  // [kk][k-row]  16.9 KB
  const int bh  = blockIdx.z;
  const int q0  = blockIdx.y * 128;
  const int k0  = blockIdx.x * 128;
  const int tid = threadIdx.x;
  const float* qg = q + ((size_t)bh * kS + q0) * kD;   // 128 rows x 64
  const float* kg = k + ((size_t)bh * kS + k0) * kD;

  const int ty8 = (tid >> 4) * 8;   // q rows ty8..ty8+7
  const int tx8 = (tid & 15) * 8;   // k cols tx8..tx8+7
  f2 acc[8][4] = {};                // acc[i][j2] = cols {2*j2, 2*j2+1}

  for (int half = 0; half < 2; ++half) {
    if (half) __syncthreads();       // waves done reading previous half
#pragma unroll
    for (int rnd = 0; rnd < 4; ++rnd) {
      int flat = rnd * 1024 + tid * 4;   // 128 rows x 32 cols per half
      int r = flat >> 5;                 // tile row 0..127
      int c = flat & 31;                 // kk within half (mult of 4)
      float4 qv = *(const float4*)(qg + r * kD + half * 32 + c);
      QsT[c + 0][r] = qv.x;
      QsT[c + 1][r] = qv.y;
      QsT[c + 2][r] = qv.z;
      QsT[c + 3][r] = qv.w;
      float4 kv = *(const float4*)(kg + r * kD + half * 32 + c);
      KsT[c + 0][r] = kv.x;
      KsT[c + 1][r] = kv.y;
      KsT[c + 2][r] = kv.z;
      KsT[c + 3][r] = kv.w;
    }
    __syncthreads();

#pragma unroll
    for (int kk = 0; kk < 32; ++kk) {
      float a[8];
      f2 b[4];
      *(float4*)(&a[0]) = *(const float4*)(&QsT[kk][ty8]);
      *(float4*)(&a[4]) = *(const float4*)(&QsT[kk][ty8 + 4]);
      float4 b0 = *(const float4*)(&KsT[kk][tx8]);
      float4 b1 = *(const float4*)(&KsT[kk][tx8 + 4]);
      b[0] = f2{b0.x, b0.y};
      b[1] = f2{b0.z, b0.w};
      b[2] = f2{b1.x, b1.y};
      b[3] = f2{b1.z, b1.w};
      // Per-element d order: half outer, kk inner ascending -> frozen chain.
#pragma unroll
      for (int i = 0; i < 8; ++i) {
        const f2 as = {a[i], a[i]};
#pragma unroll
        for (int j2 = 0; j2 < 4; ++j2)
          acc[i][j2] += as * b[j2];    // -> v_pk_fma_f32 (2 fused chains)
      }
    }
  }

#pragma unroll
  for (int i = 0; i < 8; ++i) {
    float* orow = scores + ((size_t)bh * kS + q0 + ty8 + i) * kS + k0 + tx8;
    float4 o0 = make_float4(acc[i][0].x * 0.125f, acc[i][0].y * 0.125f,
                            acc[i][1].x * 0.125f, acc[i][1].y * 0.125f);
    float4 o1 = make_float4(acc[i][2].x * 0.125f, acc[i][2].y * 0.125f,
                            acc[i][3].x * 0.125f, acc[i][3].y * 0.125f);
    *(float4*)(orow)     = o0;
    *(float4*)(orow + 4) = o1;
  }
}

// ---------------------------------------------------------------------------
// Kernel 2: one WAVE per query row. R6 probe: 455 us vs ~256 us streaming
// floor -> latency/overlap starved at 4 waves/SIMD (LDS 37KB AND ~110 VGPR
// both capped occupancy). This round raises occupancy on BOTH axes:
//  - histogram packed 2 bins/word (16-bit counters, max count 2048 << 65536):
//    hist 8.25 -> 4.25 KB/wave, block LDS 37 -> ~22 KB (7 blocks/CU by LDS).
//    Pad: word w at w + (w>>4) -> lane chunk stride 17 (coprime 32, no
//    conflicts on chunk reads).
//  - w32[] register array deleted; P7 recomputes __expf(locv-pmax)
//    (bit-identical: same input, same fn) -> ~-32 VGPR; launch_bounds(256,5).
// Selection semantics FROZEN: t32 = 32nd-largest fp32 VALUE (dups counted),
// keep = score >= t32. All outputs bit-identical to R2.
// ---------------------------------------------------------------------------
__global__ __launch_bounds__(256, 5) void topk_softmax(const float* __restrict__ v,
                                                       float* __restrict__ ctx,
                                                       float* __restrict__ attn,
                                                       float* __restrict__ mask) {
  __shared__ unsigned s_hist[4][kPadWords];  // 17 KB (4.25 KB / wave)
  __shared__ float    s_cand[4][kCandCap];   // 2 KB
  __shared__ int      s_kidx[4][kKeepCap];   // 1 KB
  __shared__ float    s_kw[4][kKeepCap];     // 1 KB
  __shared__ unsigned s_nc[4];

  const int tid  = threadIdx.x;
  const int wid  = tid >> 6;
  const int lane = tid & 63;
  const int row  = blockIdx.x * 4 + wid;     // bh*2048 + qi
  const int bh   = row >> 11;
  unsigned* hist = s_hist[wid];

  // P0: load this row's 2048 scores, 32/lane (8 x float4, coalesced).
  const float* srow = attn + (size_t)row * kS;   // scores from kernel 1
  float locv[32];
#pragma unroll
  for (int g = 0; g < 8; ++g)
    *(float4*)(&locv[g * 4]) = *(const float4*)(srow + g * 256 + lane * 4);

  // zero packed hist (1088 = 17*64, stride-64 -> 2-way = free) + counter
#pragma unroll
  for (int j = 0; j < 17; ++j) hist[j * 64 + lane] = 0u;
  if (lane == 0) s_nc[wid] = 0u;

  // P1: histogram (11-bit sortable prefix; bin b -> word b>>1 padded,
  // half b&1) + row max.
  float pmax = locv[0];
#pragma unroll
  for (int j = 0; j < 32; ++j) {
    unsigned b = sortable_bits(locv[j]) >> 21;
    unsigned w = b >> 1;
    atomicAdd(&hist[w + (w >> 4)], 1u << ((b & 1) << 4));
    pmax = fmaxf(pmax, locv[j]);
  }
#pragma unroll
  for (int off = 32; off >= 1; off >>= 1)
    pmax = fmaxf(pmax, __shfl_xor(pmax, off));

  asm volatile("s_waitcnt lgkmcnt(0)" ::: "memory");

  // P2: per-lane chunk sums (bins [32*lane, 32*lane+32) = words 16L..16L+15
  // at padded idx 17L + jw) + in-wave suffix scan.
  unsigned lsum = 0;
#pragma unroll
  for (int jw = 0; jw < 16; ++jw) {
    unsigned w = hist[lane * 17 + jw];
    lsum += (w & 0xFFFFu) + (w >> 16);
  }
  unsigned sfx = lsum;
#pragma unroll
  for (int off = 1; off < 64; off <<= 1) {
    unsigned z = __shfl_down(sfx, off);
    if (lane + off < 64) sfx += z;
  }
  const unsigned above = sfx - lsum;   // elements in chunks strictly above mine

  // P3: locate pivot bin (exactly one lane crosses kTopK).
  int bstar = 0, gabove = 0;
  const bool ispiv = (sfx >= (unsigned)kTopK) && (above < (unsigned)kTopK);
  if (ispiv) {
    unsigned run = above;
    for (int j = 31; j >= 0; --j) {
      unsigned wv = hist[lane * 17 + (j >> 1)];
      unsigned h = (wv >> ((j & 1) << 4)) & 0xFFFFu;
      if (run < (unsigned)kTopK && run + h >= (unsigned)kTopK) {
        bstar  = lane * 32 + j;
        gabove = (int)run;
      }
      run += h;
    }
  }
  const unsigned long long pm = __ballot(ispiv);
  const int psrc = __ffsll(pm) - 1;
  bstar  = __shfl(bstar, psrc);
  gabove = __shfl(gabove, psrc);

  // P4: collect pivot-bin candidates (equal values all share the pivot bin).
#pragma unroll
  for (int j = 0; j < 32; ++j) {
    unsigned b = sortable_bits(locv[j]) >> 21;
    if ((int)b == bstar) {
      unsigned p = atomicAdd(&s_nc[wid], 1u);
      if (p < (unsigned)kCandCap) s_cand[wid][p] = locv[j];
    }
  }
  asm volatile("s_waitcnt lgkmcnt(0)" ::: "memory");
  const int m = (int)min(s_nc[wid], (unsigned)kCandCap);

  // P5: t32 = value with gabove+g < 32 <= gabove+g+e. Lane i refines
  // candidates i and i+64; winner found via ballot, broadcast via shfl.
  const float x0 = (lane < m) ? s_cand[wid][lane] : 0.0f;
  const float x1 = (lane + 64 < m) ? s_cand[wid][lane + 64] : 0.0f;
  int g0 = 0, e0 = 0, g1 = 0, e1 = 0;
  for (int j = 0; j < m; ++j) {
    float y = s_cand[wid][j];   // broadcast read
    g0 += (y > x0); e0 += (y == x0);
    g1 += (y > x1); e1 += (y == x1);
  }
  const bool win0 = (lane < m) &&
                    (gabove + g0 < kTopK) && (gabove + g0 + e0 >= kTopK);
  const bool win1 = (lane + 64 < m) &&
                    (gabove + g1 < kTopK) && (gabove + g1 + e1 >= kTopK);
  const unsigned long long wm0 = __ballot(win0);
  const unsigned long long wm1 = __ballot(win1);
  float t32;
  if (wm0 != 0ull)      t32 = __shfl(x0, __ffsll(wm0) - 1);
  else if (wm1 != 0ull) t32 = __shfl(x1, __ffsll(wm1) - 1);
  else                  t32 = pmax;   // unreachable (cap never hit)

  // P6: Z + kept-list via ballot/popc compaction (no LDS atomics;
  // deterministic j-major, lane-minor list order). Same numerics:
  // w = __expf(score - rowmax) for kept, 0 otherwise. No w32[] array --
  // P7 recomputes the identical expf (saves ~32 VGPR for occupancy).
  const unsigned long long below = (1ull << lane) - 1ull;
  float psum = 0.0f;
  int nkbase = 0;
#pragma unroll
  for (int j = 0; j < 32; ++j) {
    const bool keep = (locv[j] >= t32);
    const float wv = keep ? __expf(locv[j] - pmax) : 0.0f;
    psum += wv;
    const unsigned long long mk = __ballot(keep);
    if (keep) {
      const int slot = nkbase + (int)__popcll(mk & below);
      if (slot < kKeepCap) {
        s_kidx[wid][slot] = (j >> 2) * 256 + lane * 4 + (j & 3);  // key index
        s_kw[wid][slot]   = wv;
      }
    }
    nkbase += (int)__popcll(mk);
  }
  const int nk = nkbase < kKeepCap ? nkbase : kKeepCap;
#pragma unroll
  for (int off = 32; off >= 1; off >>= 1)
    psum += __shfl_xor(psum, off);
  const float invZ = 1.0f / psum;

  // P7: write attn + mask (coalesced float4); attn weight recomputed
  // bit-identically from locv.
  float* arow = attn + (size_t)row * kS;
  float* mrow = mask + (size_t)row * kS;
#pragma unroll
  for (int g = 0; g < 8; ++g) {
    float aw[4], mw[4];
#pragma unroll
    for (int u = 0; u < 4; ++u) {
      const float x = locv[g * 4 + u];
      const bool keep = (x >= t32);
      aw[u] = (keep ? __expf(x - pmax) : 0.0f) * invZ;
      mw[u] = keep ? 0.f : 1.f;
    }
    *(float4*)(arow + g * 256 + lane * 4) = make_float4(aw[0], aw[1], aw[2], aw[3]);
    *(float4*)(mrow + g * 256 + lane * 4) = make_float4(mw[0], mw[1], mw[2], mw[3]);
  }

  // P8: context. ALL 64 lanes (lane = dim d), 8-deep batched v loads (L2-hot,
  // coalesced 256B per row), single accumulator in deterministic slot order.
  asm volatile("s_waitcnt lgkmcnt(0)" ::: "memory");
  const float* vb = v + ((size_t)bh * kS) * kD + lane;
  float acc = 0.0f;
  int c = 0;
  for (; c + 8 <= nk; c += 8) {
    float w[8], vv[8];
    int   ii[8];
#pragma unroll
    for (int u = 0; u < 8; ++u) {
      w[u]  = s_kw[wid][c + u];
      ii[u] = s_kidx[wid][c + u];
    }
#pragma unroll
    for (int u = 0; u < 8; ++u)
      vv[u] = vb[(size_t)ii[u] * kD];
#pragma unroll
    for (int u = 0; u < 8; ++u)
      acc += w[u] * vv[u];
  }
  for (; c < nk; ++c)
    acc += s_kw[wid][c] * vb[(size_t)s_kidx[wid][c] * kD];
  ctx[(size_t)row * kD + lane] = acc * invZ;
}

extern "C" void kernel_launch(void* const* d_in, const int* in_sizes, int n_in,
                              void* d_out, int out_size, void* d_ws, size_t ws_size,
                              hipStream_t stream) {
  const float* q = (const float*)d_in[0];
  const float* k = (const float*)d_in[1];
  const float* v = (const float*)d_in[2];
  float* out  = (float*)d_out;
  float* ctx  = out;
  float* attn = out + kCtxElems;
  float* mask = attn + kAttnElems;

  dim3 g1(kS / 128, kS / 128, kBH);
  qk_scores<<<g1, 256, 0, stream>>>(q, k, attn);
  topk_softmax<<<dim3(kBH * kS / 4), 256, 0, stream>>>(v, ctx, attn, mask);
}

// Round 8
// 1490.270 us; speedup vs baseline: 1.2231x; 1.0306x over previous
//
#include <hip/hip_runtime.h>
#include <math.h>

namespace {
constexpr int kS = 2048;
constexpr int kD = 64;
constexpr int kBH = 32;              // B*H = 2*16
constexpr int kTopK = 32;
constexpr int kPadBins = 2112;       // 2048 bins (11-bit) + 64 pad words
constexpr int kCandCap = 128;        // pivot-bin candidates
constexpr int kKeepCap = 64;         // kept (idx, weight) list cap
constexpr size_t kCtxElems  = (size_t)kBH * kS * kD;   // 4,194,304
constexpr size_t kAttnElems = (size_t)kBH * kS * kS;   // 134,217,728
}

typedef float f2 __attribute__((ext_vector_type(2)));

__device__ __forceinline__ unsigned sortable_bits(float x) {
  unsigned u = __float_as_uint(x);
  return u ^ ((u & 0x80000000u) ? 0xFFFFFFFFu : 0x80000000u);
}

// ---------------------------------------------------------------------------
// Kernel 1: scores = Q K^T / 8, fp32. Round-2 empirical best, FROZEN.
// BIT-EXACTNESS INVARIANT: single fp32 fused-FMA chain per element, d
// ascending, *0.125f at the end; f2 pairing along j = independent chains.
// ---------------------------------------------------------------------------
__global__ __launch_bounds__(256) void qk_scores(const float* __restrict__ q,
                                                 const float* __restrict__ k,
                                                 float* __restrict__ scores) {
  __shared__ float QsT[32][132];  // [kk][q-row]  16.9 KB
  __shared__ float KsT[32][132];  // [kk][k-row]  16.9 KB
  const int bh  = blockIdx.z;
  const int q0  = blockIdx.y * 128;
  const int k0  = blockIdx.x * 128;
  const int tid = threadIdx.x;
  const float* qg = q + ((size_t)bh * kS + q0) * kD;   // 128 rows x 64
  const float* kg = k + ((size_t)bh * kS + k0) * kD;

  const int ty8 = (tid >> 4) * 8;   // q rows ty8..ty8+7
  const int tx8 = (tid & 15) * 8;   // k cols tx8..tx8+7
  f2 acc[8][4] = {};                // acc[i][j2] = cols {2*j2, 2*j2+1}

  for (int half = 0; half < 2; ++half) {
    if (half) __syncthreads();       // waves done reading previous half
#pragma unroll
    for (int rnd = 0; rnd < 4; ++rnd) {
      int flat = rnd * 1024 + tid * 4;   // 128 rows x 32 cols per half
      int r = flat >> 5;                 // tile row 0..127
      int c = flat & 31;                 // kk within half (mult of 4)
      float4 qv = *(const float4*)(qg + r * kD + half * 32 + c);
      QsT[c + 0][r] = qv.x;
      QsT[c + 1][r] = qv.y;
      QsT[c + 2][r] = qv.z;
      QsT[c + 3][r] = qv.w;
      float4 kv = *(const float4*)(kg + r * kD + half * 32 + c);
      KsT[c + 0][r] = kv.x;
      KsT[c + 1][r] = kv.y;
      KsT[c + 2][r] = kv.z;
      KsT[c + 3][r] = kv.w;
    }
    __syncthreads();

#pragma unroll
    for (int kk = 0; kk < 32; ++kk) {
      float a[8];
      f2 b[4];
      *(float4*)(&a[0]) = *(const float4*)(&QsT[kk][ty8]);
      *(float4*)(&a[4]) = *(const float4*)(&QsT[kk][ty8 + 4]);
      float4 b0 = *(const float4*)(&KsT[kk][tx8]);
      float4 b1 = *(const float4*)(&KsT[kk][tx8 + 4]);
      b[0] = f2{b0.x, b0.y};
      b[1] = f2{b0.z, b0.w};
      b[2] = f2{b1.x, b1.y};
      b[3] = f2{b1.z, b1.w};
      // Per-element d order: half outer, kk inner ascending -> frozen chain.
#pragma unroll
      for (int i = 0; i < 8; ++i) {
        const f2 as = {a[i], a[i]};
#pragma unroll
        for (int j2 = 0; j2 < 4; ++j2)
          acc[i][j2] += as * b[j2];    // -> v_pk_fma_f32 (2 fused chains)
      }
    }
  }

#pragma unroll
  for (int i = 0; i < 8; ++i) {
    float* orow = scores + ((size_t)bh * kS + q0 + ty8 + i) * kS + k0 + tx8;
    float4 o0 = make_float4(acc[i][0].x * 0.125f, acc[i][0].y * 0.125f,
                            acc[i][1].x * 0.125f, acc[i][1].y * 0.125f);
    float4 o1 = make_float4(acc[i][2].x * 0.125f, acc[i][2].y * 0.125f,
                            acc[i][3].x * 0.125f, acc[i][3].y * 0.125f);
    *(float4*)(orow)     = o0;
    *(float4*)(orow + 4) = o1;
  }
}

// ---------------------------------------------------------------------------
// Kernel 2: R2 version (the 1374-us config), with ONE addition: the entire
// selection machinery (hist zero -> P1 -> P2 -> P3 -> P4 -> P5) runs TWICE
// via an opaque trip count (no CSE possible: LDS round-trips + opaque reps).
// DIAGNOSTIC: dur_us = 1374 + t_sel. Outputs built from the final (identical)
// t32 -> bit-identical results. Decision rule pre-committed in the journal:
//   t_sel > 150us -> replace atomic histogram next round;
//   t_sel < 60us  -> selection innocent, restructure IO path next round.
// ---------------------------------------------------------------------------
__global__ __launch_bounds__(256) void topk_softmax(const float* __restrict__ v,
                                                    float* __restrict__ ctx,
                                                    float* __restrict__ attn,
                                                    float* __restrict__ mask) {
  __shared__ unsigned s_hist[4][kPadBins];   // 33 KB (8.25 KB / wave)
  __shared__ float    s_cand[4][kCandCap];   // 2 KB
  __shared__ int      s_kidx[4][kKeepCap];   // 1 KB
  __shared__ float    s_kw[4][kKeepCap];     // 1 KB
  __shared__ unsigned s_nc[4];

  const int tid  = threadIdx.x;
  const int wid  = tid >> 6;
  const int lane = tid & 63;
  const int row  = blockIdx.x * 4 + wid;     // bh*2048 + qi
  const int bh   = row >> 11;
  unsigned* hist = s_hist[wid];

  // P0: load this row's 2048 scores, 32/lane (8 x float4, coalesced).
  const float* srow = attn + (size_t)row * kS;   // scores from kernel 1
  float locv[32];
#pragma unroll
  for (int g = 0; g < 8; ++g)
    *(float4*)(&locv[g * 4]) = *(const float4*)(srow + g * 256 + lane * 4);

  float pmax;
  float t32;

  int reps = 2;                       // opaque: compiler cannot collapse reps
  asm volatile("" : "+s"(reps));
  for (int rep = 0; rep < reps; ++rep) {
    // zero padded hist (2112 = 33*64, stride-64 -> 2-way = free) + counter
#pragma unroll
    for (int j = 0; j < 33; ++j) hist[j * 64 + lane] = 0u;
    if (lane == 0) s_nc[wid] = 0u;

    // P1: histogram (11-bit sortable prefix) + row max.
    pmax = locv[0];
#pragma unroll
    for (int j = 0; j < 32; ++j) {
      unsigned b = sortable_bits(locv[j]) >> 21;
      atomicAdd(&hist[b + (b >> 5)], 1u);
      pmax = fmaxf(pmax, locv[j]);
    }
#pragma unroll
    for (int off = 32; off >= 1; off >>= 1)
      pmax = fmaxf(pmax, __shfl_xor(pmax, off));

    asm volatile("s_waitcnt lgkmcnt(0)" ::: "memory");

    // P2: per-lane chunk sums + in-wave suffix scan.
    unsigned lsum = 0;
#pragma unroll
    for (int j = 0; j < 32; ++j) lsum += hist[lane * 33 + j];   // padded idx
    unsigned sfx = lsum;
#pragma unroll
    for (int off = 1; off < 64; off <<= 1) {
      unsigned z = __shfl_down(sfx, off);
      if (lane + off < 64) sfx += z;
    }
    const unsigned above = sfx - lsum;   // elements in chunks strictly above

    // P3: locate pivot bin (exactly one lane crosses kTopK).
    int bstar = 0, gabove = 0;
    const bool ispiv = (sfx >= (unsigned)kTopK) && (above < (unsigned)kTopK);
    if (ispiv) {
      unsigned run = above;
      for (int j = 31; j >= 0; --j) {
        unsigned h = hist[lane * 33 + j];
        if (run < (unsigned)kTopK && run + h >= (unsigned)kTopK) {
          bstar  = lane * 32 + j;
          gabove = (int)run;
        }
        run += h;
      }
    }
    const unsigned long long pm = __ballot(ispiv);
    const int psrc = __ffsll(pm) - 1;
    bstar  = __shfl(bstar, psrc);
    gabove = __shfl(gabove, psrc);

    // P4: collect pivot-bin candidates.
#pragma unroll
    for (int j = 0; j < 32; ++j) {
      unsigned b = sortable_bits(locv[j]) >> 21;
      if ((int)b == bstar) {
        unsigned p = atomicAdd(&s_nc[wid], 1u);
        if (p < (unsigned)kCandCap) s_cand[wid][p] = locv[j];
      }
    }
    asm volatile("s_waitcnt lgkmcnt(0)" ::: "memory");
    const int m = (int)min(s_nc[wid], (unsigned)kCandCap);

    // P5: t32 = value with gabove+g < 32 <= gabove+g+e.
    const float x0 = (lane < m) ? s_cand[wid][lane] : 0.0f;
    const float x1 = (lane + 64 < m) ? s_cand[wid][lane + 64] : 0.0f;
    int g0 = 0, e0 = 0, g1 = 0, e1 = 0;
    for (int j = 0; j < m; ++j) {
      float y = s_cand[wid][j];   // broadcast read
      g0 += (y > x0); e0 += (y == x0);
      g1 += (y > x1); e1 += (y == x1);
    }
    const bool win0 = (lane < m) &&
                      (gabove + g0 < kTopK) && (gabove + g0 + e0 >= kTopK);
    const bool win1 = (lane + 64 < m) &&
                      (gabove + g1 < kTopK) && (gabove + g1 + e1 >= kTopK);
    const unsigned long long wm0 = __ballot(win0);
    const unsigned long long wm1 = __ballot(win1);
    if (wm0 != 0ull)      t32 = __shfl(x0, __ffsll(wm0) - 1);
    else if (wm1 != 0ull) t32 = __shfl(x1, __ffsll(wm1) - 1);
    else                  t32 = pmax;   // unreachable (cap never hit)

    asm volatile("" :: "v"(t32));       // keep each rep's result live
  }

  // P6: weights, Z, kept-list via ballot/popc compaction (deterministic
  // j-major, lane-minor order). w = __expf(score - rowmax) kept, else 0.
  const unsigned long long below = (1ull << lane) - 1ull;
  float w32[32];
  float psum = 0.0f;
  int nkbase = 0;
#pragma unroll
  for (int j = 0; j < 32; ++j) {
    const bool keep = (locv[j] >= t32);
    const float wv = keep ? __expf(locv[j] - pmax) : 0.0f;
    w32[j] = wv;
    psum += wv;
    const unsigned long long mk = __ballot(keep);
    if (keep) {
      const int slot = nkbase + (int)__popcll(mk & below);
      if (slot < kKeepCap) {
        s_kidx[wid][slot] = (j >> 2) * 256 + lane * 4 + (j & 3);  // key index
        s_kw[wid][slot]   = wv;
      }
    }
    nkbase += (int)__popcll(mk);
  }
  const int nk = nkbase < kKeepCap ? nkbase : kKeepCap;
#pragma unroll
  for (int off = 32; off >= 1; off >>= 1)
    psum += __shfl_xor(psum, off);
  const float invZ = 1.0f / psum;

  // P7: write attn + mask straight from registers (coalesced float4).
  float* arow = attn + (size_t)row * kS;
  float* mrow = mask + (size_t)row * kS;
#pragma unroll
  for (int g = 0; g < 8; ++g) {
    float4 a = make_float4(w32[g*4+0] * invZ, w32[g*4+1] * invZ,
                           w32[g*4+2] * invZ, w32[g*4+3] * invZ);
    float4 mm = make_float4(locv[g*4+0] >= t32 ? 0.f : 1.f,
                            locv[g*4+1] >= t32 ? 0.f : 1.f,
                            locv[g*4+2] >= t32 ? 0.f : 1.f,
                            locv[g*4+3] >= t32 ? 0.f : 1.f);
    *(float4*)(arow + g * 256 + lane * 4) = a;
    *(float4*)(mrow + g * 256 + lane * 4) = mm;
  }

  // P8: context. ALL 64 lanes (lane = dim d), 8-deep batched v loads.
  asm volatile("s_waitcnt lgkmcnt(0)" ::: "memory");
  const float* vb = v + ((size_t)bh * kS) * kD + lane;
  float acc = 0.0f;
  int c = 0;
  for (; c + 8 <= nk; c += 8) {
    float w[8], vv[8];
    int   ii[8];
#pragma unroll
    for (int u = 0; u < 8; ++u) {
      w[u]  = s_kw[wid][c + u];
      ii[u] = s_kidx[wid][c + u];
    }
#pragma unroll
    for (int u = 0; u < 8; ++u)
      vv[u] = vb[(size_t)ii[u] * kD];
#pragma unroll
    for (int u = 0; u < 8; ++u)
      acc += w[u] * vv[u];
  }
  for (; c < nk; ++c)
    acc += s_kw[wid][c] * vb[(size_t)s_kidx[wid][c] * kD];
  ctx[(size_t)row * kD + lane] = acc * invZ;
}

extern "C" void kernel_launch(void* const* d_in, const int* in_sizes, int n_in,
                              void* d_out, int out_size, void* d_ws, size_t ws_size,
                              hipStream_t stream) {
  const float* q = (const float*)d_in[0];
  const float* k = (const float*)d_in[1];
  const float* v = (const float*)d_in[2];
  float* out  = (float*)d_out;
  float* ctx  = out;
  float* attn = out + kCtxElems;
  float* mask = attn + kAttnElems;

  dim3 g1(kS / 128, kS / 128, kBH);
  qk_scores<<<g1, 256, 0, stream>>>(q, k, attn);
  topk_softmax<<<dim3(kBH * kS / 4), 256, 0, stream>>>(v, ctx, attn, mask);
}

// Round 9
// 1380.024 us; speedup vs baseline: 1.3208x; 1.0799x over previous
//
#include <hip/hip_runtime.h>
#include <math.h>

namespace {
constexpr int kS = 2048;
constexpr int kD = 64;
constexpr int kBH = 32;              // B*H = 2*16
constexpr int kTopK = 32;
constexpr int kCandCap = 128;        // candidate buffer (bisection exits at <=96)
constexpr int kKeepCap = 64;         // kept (idx, weight) list cap
constexpr size_t kCtxElems  = (size_t)kBH * kS * kD;   // 4,194,304
constexpr size_t kAttnElems = (size_t)kBH * kS * kS;   // 134,217,728
}

typedef float f2 __attribute__((ext_vector_type(2)));

__device__ __forceinline__ unsigned sortable_bits(float x) {
  unsigned u = __float_as_uint(x);
  return u ^ ((u & 0x80000000u) ? 0xFFFFFFFFu : 0x80000000u);
}

__device__ __forceinline__ float unsortable_float(unsigned s) {
  return __uint_as_float(s ^ ((s & 0x80000000u) ? 0x80000000u : 0xFFFFFFFFu));
}

// ---------------------------------------------------------------------------
// Kernel 1: scores = Q K^T / 8, fp32. Round-2 empirical best, FROZEN.
// BIT-EXACTNESS INVARIANT: single fp32 fused-FMA chain per element, d
// ascending, *0.125f at the end; f2 pairing along j = independent chains.
// ---------------------------------------------------------------------------
__global__ __launch_bounds__(256) void qk_scores(const float* __restrict__ q,
                                                 const float* __restrict__ k,
                                                 float* __restrict__ scores) {
  __shared__ float QsT[32][132];  // [kk][q-row]  16.9 KB
  __shared__ float KsT[32][132];  // [kk][k-row]  16.9 KB
  const int bh  = blockIdx.z;
  const int q0  = blockIdx.y * 128;
  const int k0  = blockIdx.x * 128;
  const int tid = threadIdx.x;
  const float* qg = q + ((size_t)bh * kS + q0) * kD;   // 128 rows x 64
  const float* kg = k + ((size_t)bh * kS + k0) * kD;

  const int ty8 = (tid >> 4) * 8;   // q rows ty8..ty8+7
  const int tx8 = (tid & 15) * 8;   // k cols tx8..tx8+7
  f2 acc[8][4] = {};                // acc[i][j2] = cols {2*j2, 2*j2+1}

  for (int half = 0; half < 2; ++half) {
    if (half) __syncthreads();       // waves done reading previous half
#pragma unroll
    for (int rnd = 0; rnd < 4; ++rnd) {
      int flat = rnd * 1024 + tid * 4;   // 128 rows x 32 cols per half
      int r = flat >> 5;                 // tile row 0..127
      int c = flat & 31;                 // kk within half (mult of 4)
      float4 qv = *(const float4*)(qg + r * kD + half * 32 + c);
      QsT[c + 0][r] = qv.x;
      QsT[c + 1][r] = qv.y;
      QsT[c + 2][r] = qv.z;
      QsT[c + 3][r] = qv.w;
      float4 kv = *(const float4*)(kg + r * kD + half * 32 + c);
      KsT[c + 0][r] = kv.x;
      KsT[c + 1][r] = kv.y;
      KsT[c + 2][r] = kv.z;
      KsT[c + 3][r] = kv.w;
    }
    __syncthreads();

#pragma unroll
    for (int kk = 0; kk < 32; ++kk) {
      float a[8];
      f2 b[4];
      *(float4*)(&a[0]) = *(const float4*)(&QsT[kk][ty8]);
      *(float4*)(&a[4]) = *(const float4*)(&QsT[kk][ty8 + 4]);
      float4 b0 = *(const float4*)(&KsT[kk][tx8]);
      float4 b1 = *(const float4*)(&KsT[kk][tx8 + 4]);
      b[0] = f2{b0.x, b0.y};
      b[1] = f2{b0.z, b0.w};
      b[2] = f2{b1.x, b1.y};
      b[3] = f2{b1.z, b1.w};
      // Per-element d order: half outer, kk inner ascending -> frozen chain.
#pragma unroll
      for (int i = 0; i < 8; ++i) {
        const f2 as = {a[i], a[i]};
#pragma unroll
        for (int j2 = 0; j2 < 4; ++j2)
          acc[i][j2] += as * b[j2];    // -> v_pk_fma_f32 (2 fused chains)
      }
    }
  }

#pragma unroll
  for (int i = 0; i < 8; ++i) {
    float* orow = scores + ((size_t)bh * kS + q0 + ty8 + i) * kS + k0 + tx8;
    float4 o0 = make_float4(acc[i][0].x * 0.125f, acc[i][0].y * 0.125f,
                            acc[i][1].x * 0.125f, acc[i][1].y * 0.125f);
    float4 o1 = make_float4(acc[i][2].x * 0.125f, acc[i][2].y * 0.125f,
                            acc[i][3].x * 0.125f, acc[i][3].y * 0.125f);
    *(float4*)(orow)     = o0;
    *(float4*)(orow + 4) = o1;
  }
}

// ---------------------------------------------------------------------------
// Kernel 2: one WAVE per query row. ONE change vs the 1374-us R2 config:
// the LDS-histogram selection (hist zero + 32 LDS atomics + scan + pivot walk
// + atomic candidate append; R8 probe: 116 us, 5 serialized LDS round-trips)
// is replaced by BALLOT BISECTION in sortable-bits space -- pure VALU/SALU,
// no LDS, no atomics, no waits:
//   count(v >= fmid) via 32x popcll(ballot(...)); halve [lo,hi) until
//   <= 96 candidates; collect them (ballot-compacted) and run the UNCHANGED
//   O(m^2) float-space refine with gabove = count(v >= fhi).
// Exactness: invariant count(>=lo) >= 32 > count(>=hi); candidates complete
// for [flo, fhi) by float compare; refine identical -> t32 is still exactly
// the 32nd-largest fp32 VALUE (dups counted). Width-1 interval => all
// interval values equal => t32 = flo. Outputs bit-identical; P0/P6/P7/P8
// and kernel 1 byte-identical to R2.
// ---------------------------------------------------------------------------
__global__ __launch_bounds__(256) void topk_softmax(const float* __restrict__ v,
                                                    float* __restrict__ ctx,
                                                    float* __restrict__ attn,
                                                    float* __restrict__ mask) {
  __shared__ float    s_cand[4][kCandCap];   // 2 KB
  __shared__ int      s_kidx[4][kKeepCap];   // 1 KB
  __shared__ float    s_kw[4][kKeepCap];     // 1 KB

  const int tid  = threadIdx.x;
  const int wid  = tid >> 6;
  const int lane = tid & 63;
  const int row  = blockIdx.x * 4 + wid;     // bh*2048 + qi
  const int bh   = row >> 11;

  // P0: load this row's 2048 scores, 32/lane (8 x float4, coalesced).
  const float* srow = attn + (size_t)row * kS;   // scores from kernel 1
  float locv[32];
#pragma unroll
  for (int g = 0; g < 8; ++g)
    *(float4*)(&locv[g * 4]) = *(const float4*)(srow + g * 256 + lane * 4);

  const unsigned long long below = (1ull << lane) - 1ull;

  // P1: row max (chain identical to prior rounds).
  float pmax = locv[0];
#pragma unroll
  for (int j = 0; j < 32; ++j) pmax = fmaxf(pmax, locv[j]);
#pragma unroll
  for (int off = 32; off >= 1; off >>= 1)
    pmax = fmaxf(pmax, __shfl_xor(pmax, off));

  // P2: ballot bisection on sortable bits. Invariant:
  //   count(v >= uns(lo)) = cnt_lo >= 32 > cnt_hi = count(v >= uns(hi)).
  // (lo=0 cannot survive the loop: cnt_hi < 32 forces cnt_lo-cnt_hi > 96
  //  while cnt_lo is still 2048, so lo moves before any exit.)
  unsigned lo = 0u, hi = sortable_bits(pmax) + 1u;
  int cnt_lo = kS, cnt_hi = 0;
  while ((cnt_lo - cnt_hi > 96) && (hi - lo > 1u)) {
    const unsigned mid = lo + ((hi - lo) >> 1);
    const float fmid = unsortable_float(mid);
    int c = 0;
#pragma unroll
    for (int j = 0; j < 32; ++j)
      c += (int)__popcll(__ballot(locv[j] >= fmid));
    if (c >= kTopK) { lo = mid; cnt_lo = c; }
    else            { hi = mid; cnt_hi = c; }
  }
  const float flo = unsortable_float(lo);
  const float fhi = unsortable_float(hi);

  float t32;
  if (hi - lo == 1u) {
    // Interval is a single bit pattern: every value in it equals flo, and
    // count(>=flo) >= 32 > count(>=fhi) puts the 32nd-largest at flo.
    t32 = flo;
  } else {
    // P4': collect candidates in [flo, fhi), ballot-compacted (no atomics,
    // deterministic j-major lane-minor order). m = cnt_lo - cnt_hi <= 96.
    int nc = 0;
#pragma unroll
    for (int j = 0; j < 32; ++j) {
      const bool in = (locv[j] >= flo) && (locv[j] < fhi);
      const unsigned long long mk = __ballot(in);
      if (in) s_cand[wid][nc + (int)__popcll(mk & below)] = locv[j];
      nc += (int)__popcll(mk);
    }
    asm volatile("s_waitcnt lgkmcnt(0)" ::: "memory");
    const int m = nc;
    const int gabove = cnt_hi;   // count of values >= fhi (strictly above set)

    // P5: unchanged float-space refine: t32 = x with
    // gabove + g < 32 <= gabove + g + e.
    const float x0 = (lane < m) ? s_cand[wid][lane] : 0.0f;
    const float x1 = (lane + 64 < m) ? s_cand[wid][lane + 64] : 0.0f;
    int g0 = 0, e0 = 0, g1 = 0, e1 = 0;
    for (int j = 0; j < m; ++j) {
      float y = s_cand[wid][j];   // broadcast read
      g0 += (y > x0); e0 += (y == x0);
      g1 += (y > x1); e1 += (y == x1);
    }
    const bool win0 = (lane < m) &&
                      (gabove + g0 < kTopK) && (gabove + g0 + e0 >= kTopK);
    const bool win1 = (lane + 64 < m) &&
                      (gabove + g1 < kTopK) && (gabove + g1 + e1 >= kTopK);
    const unsigned long long wm0 = __ballot(win0);
    const unsigned long long wm1 = __ballot(win1);
    if (wm0 != 0ull)      t32 = __shfl(x0, __ffsll(wm0) - 1);
    else if (wm1 != 0ull) t32 = __shfl(x1, __ffsll(wm1) - 1);
    else                  t32 = pmax;   // unreachable
  }

  // P6: weights, Z, kept-list via ballot/popc compaction (deterministic
  // j-major, lane-minor order). w = __expf(score - rowmax) kept, else 0.
  float w32[32];
  float psum = 0.0f;
  int nkbase = 0;
#pragma unroll
  for (int j = 0; j < 32; ++j) {
    const bool keep = (locv[j] >= t32);
    const float wv = keep ? __expf(locv[j] - pmax) : 0.0f;
    w32[j] = wv;
    psum += wv;
    const unsigned long long mk = __ballot(keep);
    if (keep) {
      const int slot = nkbase + (int)__popcll(mk & below);
      if (slot < kKeepCap) {
        s_kidx[wid][slot] = (j >> 2) * 256 + lane * 4 + (j & 3);  // key index
        s_kw[wid][slot]   = wv;
      }
    }
    nkbase += (int)__popcll(mk);
  }
  const int nk = nkbase < kKeepCap ? nkbase : kKeepCap;
#pragma unroll
  for (int off = 32; off >= 1; off >>= 1)
    psum += __shfl_xor(psum, off);
  const float invZ = 1.0f / psum;

  // P7: write attn + mask straight from registers (coalesced float4).
  float* arow = attn + (size_t)row * kS;
  float* mrow = mask + (size_t)row * kS;
#pragma unroll
  for (int g = 0; g < 8; ++g) {
    float4 a = make_float4(w32[g*4+0] * invZ, w32[g*4+1] * invZ,
                           w32[g*4+2] * invZ, w32[g*4+3] * invZ);
    float4 mm = make_float4(locv[g*4+0] >= t32 ? 0.f : 1.f,
                            locv[g*4+1] >= t32 ? 0.f : 1.f,
                            locv[g*4+2] >= t32 ? 0.f : 1.f,
                            locv[g*4+3] >= t32 ? 0.f : 1.f);
    *(float4*)(arow + g * 256 + lane * 4) = a;
    *(float4*)(mrow + g * 256 + lane * 4) = mm;
  }

  // P8: context. ALL 64 lanes (lane = dim d), 8-deep batched v loads.
  asm volatile("s_waitcnt lgkmcnt(0)" ::: "memory");
  const float* vb = v + ((size_t)bh * kS) * kD + lane;
  float acc = 0.0f;
  int c = 0;
  for (; c + 8 <= nk; c += 8) {
    float w[8], vv[8];
    int   ii[8];
#pragma unroll
    for (int u = 0; u < 8; ++u) {
      w[u]  = s_kw[wid][c + u];
      ii[u] = s_kidx[wid][c + u];
    }
#pragma unroll
    for (int u = 0; u < 8; ++u)
      vv[u] = vb[(size_t)ii[u] * kD];
#pragma unroll
    for (int u = 0; u < 8; ++u)
      acc += w[u] * vv[u];
  }
  for (; c < nk; ++c)
    acc += s_kw[wid][c] * vb[(size_t)s_kidx[wid][c] * kD];
  ctx[(size_t)row * kD + lane] = acc * invZ;
}

extern "C" void kernel_launch(void* const* d_in, const int* in_sizes, int n_in,
                              void* d_out, int out_size, void* d_ws, size_t ws_size,
                              hipStream_t stream) {
  const float* q = (const float*)d_in[0];
  const float* k = (const float*)d_in[1];
  const float* v = (const float*)d_in[2];
  float* out  = (float*)d_out;
  float* ctx  = out;
  float* attn = out + kCtxElems;
  float* mask = attn + kAttnElems;

  dim3 g1(kS / 128, kS / 128, kBH);
  qk_scores<<<g1, 256, 0, stream>>>(q, k, attn);
  topk_softmax<<<dim3(kBH * kS / 4), 256, 0, stream>>>(v, ctx, attn, mask);
}